// Round 13
// baseline (139.529 us; speedup 1.0000x reference)
//
#include <hip/hip_runtime.h>
#include <hip/hip_bf16.h>
#include <math.h>

#define B_ 2
#define S_ 2048
#define D_ 256
#define QK_ 256
#define H_ 8
#define HD_ 32
#define MLP_ 1024
#define TOPK_ 8
#define R_ 2048
#define MD_ 64
#define MAXN_ 192

using bf16_t = __hip_bfloat16;
using bf16x8 = __attribute__((ext_vector_type(8))) short;   // 8 bf16 (4 VGPRs)
using f32x4  = __attribute__((ext_vector_type(4))) float;   // 4 fp32 acc

__device__ __constant__ float SCALE_ = 0.17677669529663687f;

__device__ inline float bf2f(short s) {
    union { unsigned int u; float f; } cvt;
    cvt.u = ((unsigned int)(unsigned short)s) << 16;
    return cvt.f;
}

__device__ inline bool adj_on(const void* adj, int isbyte, long idx) {
    if (isbyte) return ((const unsigned char*)adj)[idx] != 0;
    return ((const int*)adj)[idx] != 0;
}

// ---------------- region memory normalize -> bf16 nm_bf[2048][64] ----------------
__global__ void norm_rm(const float* __restrict__ rm, bf16_t* __restrict__ nm_bf) {
    int r = blockIdx.x, t = threadIdx.x;   // 64 threads
    float v = rm[r * MD_ + t];
    float s = v * v;
    for (int o = 32; o > 0; o >>= 1) s += __shfl_down(s, o);
    s = __shfl(s, 0);
    nm_bf[r * MD_ + t] = __float2bfloat16(v / (sqrtf(s) + 1e-8f));
}

// ---------------- top-8 selection from precomputed sim rows: 1 wave/region, 0 barriers ----------------
__global__ __launch_bounds__(256) void topk_sel(const float* __restrict__ sim,
                                                int* __restrict__ tk) {
    int t = threadIdx.x;
    int w = t >> 6, ln = t & 63;
    int r = blockIdx.x * 4 + w;
    const float4* row4 = (const float4*)(sim + (long)r * R_);
    float4 f4[8];
#pragma unroll
    for (int k = 0; k < 8; k++) f4[k] = row4[ln + 64 * k];   // c = 4*(ln+64k)+j
    {   // diagonal exclusion: c == r
        int rem = (r >> 2) & 63, kw = r >> 8, jw = r & 3;
        if (rem == ln) {
#pragma unroll
            for (int k = 0; k < 8; k++)
                if (k == kw) {
                    if (jw == 0) f4[k].x = -INFINITY;
                    else if (jw == 1) f4[k].y = -INFINITY;
                    else if (jw == 2) f4[k].z = -INFINITY;
                    else f4[k].w = -INFINITY;
                }
        }
    }
    for (int it = 0; it < TOPK_; it++) {
        float bv = -INFINITY; int bi = 0x7fffffff;
#pragma unroll
        for (int k = 0; k < 8; k++) {
            int c0 = 4 * (ln + 64 * k);
            if (f4[k].x > bv) { bv = f4[k].x; bi = c0; }
            if (f4[k].y > bv) { bv = f4[k].y; bi = c0 + 1; }
            if (f4[k].z > bv) { bv = f4[k].z; bi = c0 + 2; }
            if (f4[k].w > bv) { bv = f4[k].w; bi = c0 + 3; }
        }
#pragma unroll
        for (int o = 32; o > 0; o >>= 1) {
            float ov = __shfl_down(bv, o); int oi = __shfl_down(bi, o);
            if (ov > bv || (ov == bv && oi < bi)) { bv = ov; bi = oi; }
        }
        int xi = __shfl(bi, 0);
        if (ln == 0) tk[r * TOPK_ + it] = xi;
        int rem = (xi >> 2) & 63, kw = xi >> 8, jw = xi & 3;
        if (rem == ln) {
#pragma unroll
            for (int k = 0; k < 8; k++)
                if (k == kw) {
                    if (jw == 0) f4[k].x = -INFINITY;
                    else if (jw == 1) f4[k].y = -INFINITY;
                    else if (jw == 2) f4[k].z = -INFINITY;
                    else f4[k].w = -INFINITY;
                }
        }
    }
}

// ---------------- neighbor list build (adj union topk); per-row local dtype detect ----------------
__global__ __launch_bounds__(256) void build_nbr(const void* __restrict__ adj,
                                                 const int* __restrict__ tk,
                                                 int* __restrict__ nbr_idx,
                                                 int* __restrict__ nbr_cnt) {
    __shared__ int cnt, bflag;
    int r = blockIdx.x, t = threadIdx.x;
    if (t == 0) { cnt = 0; bflag = 0; }
    __syncthreads();
    // per-row dtype detect: words r*512..r*512+511 are exactly row r's bytes if
    // byte-packed (any word >1 => bytes); under int32 they are 0/1 values => no hit.
    {
        const unsigned int* rw = (const unsigned int*)adj + (long)r * 512;
        int found = 0;
        for (int i = t; i < 512; i += 256)
            if (rw[i] > 1u) found = 1;
        if (found) atomicOr(&bflag, 1);
    }
    __syncthreads();
    int isbyte = bflag;
    for (int c = t; c < S_; c += 256) {
        long idx = (long)r * R_ + c;
        if (adj_on(adj, isbyte, idx)) {
            int p = atomicAdd(&cnt, 1);
            if (p < MAXN_) nbr_idx[r * MAXN_ + p] = c;
        }
    }
    __syncthreads();
    if (t < TOPK_) {
        int c = tk[r * TOPK_ + t];
        long idx = (long)r * R_ + c;
        if (!adj_on(adj, isbyte, idx) && c < S_) {
            int p = atomicAdd(&cnt, 1);
            if (p < MAXN_) nbr_idx[r * MAXN_ + p] = c;
        }
    }
    __syncthreads();
    if (t == 0) nbr_cnt[r] = min(cnt, MAXN_);
}

// ---------------- LN1 (row/block) -> xn_bf + xcat copy + gatep bias pre-init ----------------
__global__ __launch_bounds__(256) void ln_kernel(const float* __restrict__ x,
                                                 const float* __restrict__ g,
                                                 const float* __restrict__ b,
                                                 const float* __restrict__ gb,
                                                 bf16_t* __restrict__ y,
                                                 bf16_t* __restrict__ xcat,
                                                 float* __restrict__ gatep) {
    __shared__ float red[256];
    int row = blockIdx.x, t = threadIdx.x;
    float v = x[(long)row * D_ + t];
    xcat[(long)row * 512 + t] = __float2bfloat16(v);
    gatep[(long)row * D_ + t] = gb[t];            // split-K gate GEMM accumulates on top
    red[t] = v; __syncthreads();
    for (int o = 128; o > 0; o >>= 1) { if (t < o) red[t] += red[t + o]; __syncthreads(); }
    float mean = red[0] / D_;
    __syncthreads();
    float dv = v - mean;
    red[t] = dv * dv; __syncthreads();
    for (int o = 128; o > 0; o >>= 1) { if (t < o) red[t] += red[t + o]; __syncthreads(); }
    float var = red[0] / D_;
    y[(long)row * D_ + t] = __float2bfloat16(dv * rsqrtf(var + 1e-5f) * g[t] + b[t]);
}

// ---------------- weight transpose+convert + bqkv concat + vs zero ----------------
__global__ __launch_bounds__(256) void conv_w(const float* w0, const float* w1, const float* w2,
                                              const float* w3, const float* w4, const float* w5,
                                              const float* w6,
                                              const float* bq, const float* bk, const float* bv,
                                              bf16_t* wt, float* bqkv, float* vs) {
    __shared__ float tile[32][33];
    int tb = blockIdx.x, t = threadIdx.x;
    if (tb == 899) {                              // vs zero (512 floats)
        vs[t] = 0.f; vs[t + 256] = 0.f;
        return;
    }
    if (tb >= 896) {                              // bias concat blocks
        int tt = (tb - 896) * 256 + t;            // 0..767
        if (tt < 768) bqkv[tt] = tt < 256 ? bq[tt] : (tt < 512 ? bk[tt - 256] : bv[tt - 512]);
        return;
    }
    const float* W; long dstoff; int K, N, local;
    if (tb < 64)       { W = w0; dstoff = 0;       K = 256;  N = 256;  local = tb; }
    else if (tb < 128) { W = w1; dstoff = 65536;   K = 256;  N = 256;  local = tb - 64; }
    else if (tb < 192) { W = w2; dstoff = 131072;  K = 256;  N = 256;  local = tb - 128; }
    else if (tb < 256) { W = w3; dstoff = 196608;  K = 256;  N = 256;  local = tb - 192; }
    else if (tb < 384) { W = w4; dstoff = 262144;  K = 512;  N = 256;  local = tb - 256; }
    else if (tb < 640) { W = w5; dstoff = 393216;  K = 256;  N = 1024; local = tb - 384; }
    else               { W = w6; dstoff = 655360;  K = 1024; N = 256;  local = tb - 640; }
    int ntn = N >> 5;
    int tk2 = local / ntn, tn = local - tk2 * ntn;
    int k0 = tk2 * 32, n0 = tn * 32;
    int r = t >> 5, c = t & 31;
#pragma unroll
    for (int rr = 0; rr < 4; rr++)
        tile[r + rr * 8][c] = W[(long)(k0 + r + rr * 8) * N + n0 + c];
    __syncthreads();
    bf16_t* dst = wt + dstoff;
#pragma unroll
    for (int rr = 0; rr < 4; rr++)
        dst[(long)(n0 + r + rr * 8) * K + k0 + c] = __float2bfloat16(tile[c][r + rr * 8]);
}

// ---------------- MFMA bf16 GEMM, 64x64 tile, BK=64 ----------------
#define LDT64 72

template<int GELU, int ATOMIC>
__global__ __launch_bounds__(256) void mgemm64(const bf16_t* __restrict__ A, int lda,
                                               const bf16_t* __restrict__ Bt, int ldb,
                                               const float* __restrict__ bias,
                                               float* __restrict__ Cf, int ldcf,
                                               bf16_t* __restrict__ Cb, int ldcb,
                                               float* __restrict__ vsat, int K) {
    __shared__ short As[64 * LDT64];
    __shared__ short Bs[64 * LDT64];
    int tid = threadIdx.x;
    int m0 = blockIdx.y * 64, n0 = blockIdx.x * 64;
    int w = tid >> 6, ln = tid & 63;
    int wr = w >> 1, wc = w & 1;
    int srow = tid >> 2, skb = (tid & 3) * 8;
    f32x4 zero4 = {0.f, 0.f, 0.f, 0.f};
    f32x4 acc[2][2];
#pragma unroll
    for (int i = 0; i < 2; i++)
#pragma unroll
        for (int j = 0; j < 2; j++) acc[i][j] = zero4;

    const bf16_t* Ab = A + (long)m0 * lda + skb;
    const bf16_t* Bb = Bt + (long)n0 * ldb + skb;
    int kbeg = ATOMIC ? blockIdx.z * K : 0;

    for (int k0 = kbeg; k0 < kbeg + K; k0 += 64) {
        uint4 a0 = *(const uint4*)(Ab + (long)srow * lda + k0);
        uint4 a1 = *(const uint4*)(Ab + (long)srow * lda + k0 + 32);
        uint4 b0 = *(const uint4*)(Bb + (long)srow * ldb + k0);
        uint4 b1 = *(const uint4*)(Bb + (long)srow * ldb + k0 + 32);
        *(uint4*)(&As[srow * LDT64 + skb]) = a0;
        *(uint4*)(&As[srow * LDT64 + skb + 32]) = a1;
        *(uint4*)(&Bs[srow * LDT64 + skb]) = b0;
        *(uint4*)(&Bs[srow * LDT64 + skb + 32]) = b1;
        __syncthreads();
        int kr = (ln >> 4) * 8;
        int arow = wr * 32 + (ln & 15);
        int brow = wc * 32 + (ln & 15);
        bf16x8 af[2][2], bfr[2][2];
#pragma unroll
        for (int mi = 0; mi < 2; mi++)
#pragma unroll
            for (int ks = 0; ks < 2; ks++)
                af[mi][ks] = *(const bf16x8*)(&As[(arow + mi * 16) * LDT64 + ks * 32 + kr]);
#pragma unroll
        for (int ni = 0; ni < 2; ni++)
#pragma unroll
            for (int ks = 0; ks < 2; ks++)
                bfr[ni][ks] = *(const bf16x8*)(&Bs[(brow + ni * 16) * LDT64 + ks * 32 + kr]);
#pragma unroll
        for (int mi = 0; mi < 2; mi++)
#pragma unroll
            for (int ni = 0; ni < 2; ni++) {
                acc[mi][ni] = __builtin_amdgcn_mfma_f32_16x16x32_bf16(af[mi][0], bfr[ni][0], acc[mi][ni], 0, 0, 0);
                acc[mi][ni] = __builtin_amdgcn_mfma_f32_16x16x32_bf16(af[mi][1], bfr[ni][1], acc[mi][ni], 0, 0, 0);
            }
        __syncthreads();
    }
    // epilogue: D[row=(l>>4)*4+r][col=l&15] per 16x16 frag (m89-verified layout)
    int colb = n0 + wc * 32 + (ln & 15);
    int rowb = m0 + wr * 32 + (ln >> 4) * 4;
#pragma unroll
    for (int ni = 0; ni < 2; ni++) {
        int col = colb + ni * 16;
        float bv = bias ? bias[col] : 0.f;
        float vcol = 0.f;
#pragma unroll
        for (int mi = 0; mi < 2; mi++) {
#pragma unroll
            for (int r = 0; r < 4; r++) {
                int row = rowb + mi * 16 + r;
                float v = acc[mi][ni][r] + bv;
                if (GELU) v = 0.5f * v * (1.0f + erff(v * 0.70710678118654752f));
                if (ATOMIC) atomicAdd(&Cf[(long)row * ldcf + col], v);
                else if (Cf) Cf[(long)row * ldcf + col] = v;
                if (Cb) Cb[(long)row * ldcb + col] = __float2bfloat16(v);
                vcol += v;
            }
        }
        // v-column sums for attention (QKV GEMM only): per (batch, col) fp32 atomics
        if (vsat && col >= 512)
            atomicAdd(&vsat[((m0 >> 11) << 8) + (col - 512)], vcol);
    }
}

// ---------------- sparse attention: quad-coop coalesced K loads, wave-parallel softmax ----------------
__global__ __launch_bounds__(256) void attn_kernel(const bf16_t* __restrict__ qkv,
                                                   const float* __restrict__ vs,
                                                   const int* __restrict__ ridx,
                                                   const int* __restrict__ nbr_idx,
                                                   const int* __restrict__ nbr_cnt,
                                                   bf16_t* __restrict__ out) {
    __shared__ float qs[QK_];
    __shared__ float ej[H_][MAXN_];
    __shared__ int   nb[MAXN_];
    int bi = blockIdx.x;              // b*S + i
    int b = bi >> 11, i = bi & (S_ - 1);
    int t = threadIdx.x;
    int h = t >> 5, ln = t & 31;
    int r = ridx[i];
    int cnt = nbr_cnt[r];
    qs[t] = __bfloat162float(qkv[(long)bi * 768 + t]);
    for (int p = t; p < cnt; p += 256) nb[p] = nbr_idx[r * MAXN_ + p];
    __syncthreads();
    const bf16_t* kvb = qkv + (long)b * S_ * 768;
    int quad = ln & 3, pslot = ln >> 2;
    const float* qh = qs + h * HD_;
    float qreg[8];
#pragma unroll
    for (int e = 0; e < 8; e++) qreg[e] = qh[quad * 8 + e];
    float lmax = 0.0f;                // masked zeros always present (cnt << S)
#pragma unroll 2
    for (int s = 0; s * 8 < cnt; s++) {
        int p = s * 8 + pslot;
        float sc = 0.f;
        if (p < cnt) {
            int j = nb[p];
            bf16x8 kk = *(const bf16x8*)(kvb + (long)j * 768 + 256 + h * HD_ + quad * 8);
#pragma unroll
            for (int e = 0; e < 8; e++) sc = fmaf(qreg[e], bf2f(kk[e]), sc);
        }
        sc += __shfl_xor(sc, 1, 32);
        sc += __shfl_xor(sc, 2, 32);
        sc *= SCALE_;
        if (p < cnt) {
            if (quad == 0) ej[h][p] = sc;   // raw score; same-wave LDS ordering
            lmax = fmaxf(lmax, sc);
        }
    }
#pragma unroll
    for (int o = 16; o > 0; o >>= 1) lmax = fmaxf(lmax, __shfl_xor(lmax, o, 32));
    float lz = 0.f;
#pragma unroll
    for (int u = 0; u < 6; u++) {
        int p = ln + 32 * u;
        if (p < cnt) {
            float e = expf(ej[h][p] - lmax);
            ej[h][p] = e;
            lz += e;
        }
    }
#pragma unroll
    for (int o = 16; o > 0; o >>= 1) lz += __shfl_xor(lz, o, 32);
    float em = expf(-lmax);
    float Z = lz + (float)(S_ - cnt) * em;
    float accv = 0.f, vn = 0.f;
    const bf16_t* vbase = kvb + 512 + h * HD_ + ln;
#pragma unroll 8
    for (int p = 0; p < cnt; p++) {
        int j = nb[p];
        float vv = __bfloat162float(vbase[(long)j * 768]);
        float e = ej[h][p];
        accv = fmaf(e, vv, accv);
        vn += vv;
    }
    float o = (em * (vs[b * QK_ + h * HD_ + ln] - vn) + accv) / Z;
    out[(long)bi * QK_ + h * HD_ + ln] = __float2bfloat16(o);
}

// ---------------- gate + fuse + LN2: writes out = fused + fb2 (FFN2 accumulates), h bf16 ----------------
__global__ __launch_bounds__(256) void fuse_ln2_kernel(const float* __restrict__ x,
                                                       const float* __restrict__ ao,
                                                       const float* __restrict__ gp,
                                                       const float* __restrict__ g2,
                                                       const float* __restrict__ b2,
                                                       const float* __restrict__ fb2,
                                                       float* __restrict__ out,
                                                       bf16_t* __restrict__ h) {
    __shared__ float red[256];
    int row = blockIdx.x, t = threadIdx.x;
    long idx = (long)row * D_ + t;
    float gate = 1.f / (1.f + expf(-gp[idx]));
    float f = gate * x[idx] + (1.f - gate) * ao[idx];
    out[idx] = f + fb2[t];            // FFN2 split-K atomically accumulates on top
    red[t] = f; __syncthreads();
    for (int o = 128; o > 0; o >>= 1) { if (t < o) red[t] += red[t + o]; __syncthreads(); }
    float mean = red[0] / D_;
    __syncthreads();
    float dv = f - mean;
    red[t] = dv * dv; __syncthreads();
    for (int o = 128; o > 0; o >>= 1) { if (t < o) red[t] += red[t + o]; __syncthreads(); }
    float var = red[0] / D_;
    h[idx] = __float2bfloat16(dv * rsqrtf(var + 1e-5f) * g2[t] + b2[t]);
}

extern "C" void kernel_launch(void* const* d_in, const int* in_sizes, int n_in,
                              void* d_out, int out_size, void* d_ws, size_t ws_size,
                              hipStream_t stream) {
    const float* x    = (const float*)d_in[0];
    const int*   ridx = (const int*)d_in[1];
    const void*  adj  = d_in[2];
    const float* rm   = (const float*)d_in[3];
    const float* wq = (const float*)d_in[4],  *bq = (const float*)d_in[5];
    const float* wk = (const float*)d_in[6],  *bk = (const float*)d_in[7];
    const float* wv = (const float*)d_in[8],  *bv = (const float*)d_in[9];
    const float* wo = (const float*)d_in[10], *bo = (const float*)d_in[11];
    const float* ln1g = (const float*)d_in[12], *ln1b = (const float*)d_in[13];
    const float* ln2g = (const float*)d_in[14], *ln2b = (const float*)d_in[15];
    const float* gw  = (const float*)d_in[16], *gb  = (const float*)d_in[17];
    const float* fw1 = (const float*)d_in[18], *fb1 = (const float*)d_in[19];
    const float* fw2 = (const float*)d_in[20], *fb2 = (const float*)d_in[21];
    float* out = (float*)d_out;

    // workspace layout (float units; all offsets 16B-aligned)
    float* wsf      = (float*)d_ws;
    bf16_t* nm_bf   = (bf16_t*)(wsf + 64);         // slot 131072 fl
    int*   tk       = (int*)(wsf + 131136);        // 16384
    int*   nbr_idx  = tk + 16384;                  // 393216
    int*   nbr_cnt  = nbr_idx + R_ * MAXN_;        // 2048
    bf16_t* qkv_bf  = (bf16_t*)(nbr_cnt + 2048);   // slot 3145728 fl
    float* vs       = (float*)(nbr_cnt + 2048) + 3145728;  // 512
    float* gatep    = vs + 512;                    // 1048576
    float* attn_out = gatep + 1048576;             // 1048576
    float* fusedb   = attn_out + 1048576;          // 1048576 (unused)
    float* part     = fusedb + 1048576;            // 32768 (unused)
    bf16_t* xn_bf   = (bf16_t*)(part + 32768);     // slot 524288 fl
    bf16_t* attnO_bf= (bf16_t*)((float*)xn_bf + 524288);    // slot 524288 fl
    bf16_t* xcat_bf = (bf16_t*)((float*)attnO_bf + 524288); // slot 1048576 fl
    bf16_t* hb_bf   = (bf16_t*)((float*)xcat_bf + 1048576); // slot 524288 fl
    bf16_t* f1_bf   = (bf16_t*)((float*)hb_bf + 524288);    // slot 2097152 fl
    bf16_t* WT      = (bf16_t*)((float*)f1_bf + 2097152);   // slot 458752 fl
    float* bqkv     = (float*)WT + 458752;         // 768
    float* sim      = bqkv + 768;                  // 4194304

    const int MROWS = B_ * S_;                     // 4096

    norm_rm<<<R_, 64, 0, stream>>>(rm, nm_bf);

    // sim = nm @ nm^T (M=N=2048, K=64)
    mgemm64<0, 0><<<dim3(R_ / 64, R_ / 64), 256, 0, stream>>>(
        nm_bf, 64, nm_bf, 64, nullptr, sim, 2048, nullptr, 0, nullptr, MD_);
    topk_sel<<<R_ / 4, 256, 0, stream>>>(sim, tk);
    build_nbr<<<R_, 256, 0, stream>>>(adj, tk, nbr_idx, nbr_cnt);

    conv_w<<<900, 256, 0, stream>>>(wq, wk, wv, wo, gw, fw1, fw2, bq, bk, bv, WT, bqkv, vs);

    ln_kernel<<<MROWS, 256, 0, stream>>>(x, ln1g, ln1b, gb, xn_bf, xcat_bf, gatep);

    // QKV: xn @ WTqkv^T -> qkv bf16; epilogue atomically accumulates vs (v column sums)
    mgemm64<0, 0><<<dim3(768 / 64, MROWS / 64), 256, 0, stream>>>(
        xn_bf, 256, WT, 256, bqkv, nullptr, 0, qkv_bf, 768, vs, 256);

    attn_kernel<<<MROWS, 256, 0, stream>>>(qkv_bf, vs, ridx, nbr_idx, nbr_cnt, attnO_bf);

    // wo: attnO @ wo^T + bo -> attn_out fp32; bf16 copy into xcat cols 256..511
    mgemm64<0, 0><<<dim3(256 / 64, MROWS / 64), 256, 0, stream>>>(
        attnO_bf, 256, WT + 196608, 256, bo, attn_out, 256, xcat_bf + 256, 512, nullptr, 256);

    // gate split-K=2: [x | attn_out] @ gw^T atomically onto gatep (pre-init = gb)
    mgemm64<0, 1><<<dim3(256 / 64, MROWS / 64, 2), 256, 0, stream>>>(
        xcat_bf, 512, WT + 262144, 512, nullptr, gatep, 256, nullptr, 0, nullptr, 256);

    fuse_ln2_kernel<<<MROWS, 256, 0, stream>>>(x, attn_out, gatep, ln2g, ln2b, fb2, out, hb_bf);

    // FFN1: h @ w1^T + b1, gelu -> f1 bf16
    mgemm64<1, 0><<<dim3(1024 / 64, MROWS / 64), 256, 0, stream>>>(
        hb_bf, 256, WT + 393216, 256, fb1, nullptr, 0, f1_bf, 1024, nullptr, 256);

    // FFN2 split-K=2: atomic accumulate onto pre-initialized out (= fused + fb2)
    mgemm64<0, 1><<<dim3(256 / 64, MROWS / 64, 2), 256, 0, stream>>>(
        f1_bf, 1024, WT + 655360, 1024, nullptr, out, 256, nullptr, 0, nullptr, 512);
}

// Round 14
// 131.788 us; speedup vs baseline: 1.0587x; 1.0587x over previous
//
#include <hip/hip_runtime.h>
#include <hip/hip_bf16.h>
#include <math.h>

#define B_ 2
#define S_ 2048
#define D_ 256
#define QK_ 256
#define H_ 8
#define HD_ 32
#define MLP_ 1024
#define TOPK_ 8
#define R_ 2048
#define MD_ 64
#define MAXN_ 192

using bf16_t = __hip_bfloat16;
using bf16x8 = __attribute__((ext_vector_type(8))) short;   // 8 bf16 (4 VGPRs)
using f32x4  = __attribute__((ext_vector_type(4))) float;   // 4 fp32 acc

__device__ __constant__ float SCALE_ = 0.17677669529663687f;

__device__ inline float bf2f(short s) {
    union { unsigned int u; float f; } cvt;
    cvt.u = ((unsigned int)(unsigned short)s) << 16;
    return cvt.f;
}

// ---------------- adj dtype detection ----------------
__global__ void detect_adj(const unsigned int* __restrict__ adj, int* __restrict__ flag) {
    long g = (long)blockIdx.x * blockDim.x + threadIdx.x;
    long n = (long)R_ * R_ / 4;
    int found = 0;
    for (long i = g; i < n; i += (long)gridDim.x * blockDim.x) {
        if (adj[i] > 1u) { found = 1; break; }
    }
    if (found) atomicOr(flag, 1);
}

__device__ inline bool adj_on(const void* adj, int isbyte, long idx) {
    if (isbyte) return ((const unsigned char*)adj)[idx] != 0;
    return ((const int*)adj)[idx] != 0;
}

// ---------------- region memory normalize -> bf16 row-major nm_bf[2048][64]; also inits flag ----------------
__global__ void norm_rm(const float* __restrict__ rm, bf16_t* __restrict__ nm_bf,
                        int* __restrict__ flag) {
    int r = blockIdx.x, t = threadIdx.x;   // 64 threads
    if (r == 0 && t == 0) *flag = 0;       // runs before detect_adj (stream order)
    float v = rm[r * MD_ + t];
    float s = v * v;
    for (int o = 32; o > 0; o >>= 1) s += __shfl_down(s, o);
    s = __shfl(s, 0);
    nm_bf[r * MD_ + t] = __float2bfloat16(v / (sqrtf(s) + 1e-8f));
}

// ---------------- top-8 selection from precomputed sim rows: 1 wave/region, 0 barriers ----------------
__global__ __launch_bounds__(256) void topk_sel(const float* __restrict__ sim,
                                                int* __restrict__ tk) {
    int t = threadIdx.x;
    int w = t >> 6, ln = t & 63;
    int r = blockIdx.x * 4 + w;
    const float4* row4 = (const float4*)(sim + (long)r * R_);
    float4 f4[8];
#pragma unroll
    for (int k = 0; k < 8; k++) f4[k] = row4[ln + 64 * k];   // c = 4*(ln+64k)+j
    {   // diagonal exclusion: c == r
        int rem = (r >> 2) & 63, kw = r >> 8, jw = r & 3;
        if (rem == ln) {
#pragma unroll
            for (int k = 0; k < 8; k++)
                if (k == kw) {
                    if (jw == 0) f4[k].x = -INFINITY;
                    else if (jw == 1) f4[k].y = -INFINITY;
                    else if (jw == 2) f4[k].z = -INFINITY;
                    else f4[k].w = -INFINITY;
                }
        }
    }
    for (int it = 0; it < TOPK_; it++) {
        float bv = -INFINITY; int bi = 0x7fffffff;
#pragma unroll
        for (int k = 0; k < 8; k++) {
            int c0 = 4 * (ln + 64 * k);
            if (f4[k].x > bv) { bv = f4[k].x; bi = c0; }
            if (f4[k].y > bv) { bv = f4[k].y; bi = c0 + 1; }
            if (f4[k].z > bv) { bv = f4[k].z; bi = c0 + 2; }
            if (f4[k].w > bv) { bv = f4[k].w; bi = c0 + 3; }
        }
#pragma unroll
        for (int o = 32; o > 0; o >>= 1) {
            float ov = __shfl_down(bv, o); int oi = __shfl_down(bi, o);
            if (ov > bv || (ov == bv && oi < bi)) { bv = ov; bi = oi; }
        }
        int xi = __shfl(bi, 0);
        if (ln == 0) tk[r * TOPK_ + it] = xi;
        int rem = (xi >> 2) & 63, kw = xi >> 8, jw = xi & 3;
        if (rem == ln) {
#pragma unroll
            for (int k = 0; k < 8; k++)
                if (k == kw) {
                    if (jw == 0) f4[k].x = -INFINITY;
                    else if (jw == 1) f4[k].y = -INFINITY;
                    else if (jw == 2) f4[k].z = -INFINITY;
                    else f4[k].w = -INFINITY;
                }
        }
    }
}

// ---------------- neighbor list build (adj union topk) ----------------
__global__ __launch_bounds__(256) void build_nbr(const void* __restrict__ adj,
                                                 const int* __restrict__ tk,
                                                 const int* __restrict__ flag,
                                                 int* __restrict__ nbr_idx,
                                                 int* __restrict__ nbr_cnt) {
    __shared__ int cnt;
    int r = blockIdx.x, t = threadIdx.x;
    if (t == 0) cnt = 0;
    __syncthreads();
    int isbyte = *flag;
    for (int c = t; c < S_; c += 256) {
        long idx = (long)r * R_ + c;
        if (adj_on(adj, isbyte, idx)) {
            int p = atomicAdd(&cnt, 1);
            if (p < MAXN_) nbr_idx[r * MAXN_ + p] = c;
        }
    }
    __syncthreads();
    if (t < TOPK_) {
        int c = tk[r * TOPK_ + t];
        long idx = (long)r * R_ + c;
        if (!adj_on(adj, isbyte, idx) && c < S_) {
            int p = atomicAdd(&cnt, 1);
            if (p < MAXN_) nbr_idx[r * MAXN_ + p] = c;
        }
    }
    __syncthreads();
    if (t == 0) nbr_cnt[r] = min(cnt, MAXN_);
}

// ---------------- layernorm (row of 256) -> bf16 out + xcat bf16 copy of x ----------------
__global__ __launch_bounds__(256) void ln_kernel(const float* __restrict__ x,
                                                 const float* __restrict__ g,
                                                 const float* __restrict__ b,
                                                 bf16_t* __restrict__ y,
                                                 bf16_t* __restrict__ xcat) {
    __shared__ float red[256];
    int row = blockIdx.x, t = threadIdx.x;
    float v = x[(long)row * D_ + t];
    xcat[(long)row * 512 + t] = __float2bfloat16(v);
    red[t] = v; __syncthreads();
    for (int o = 128; o > 0; o >>= 1) { if (t < o) red[t] += red[t + o]; __syncthreads(); }
    float mean = red[0] / D_;
    __syncthreads();
    float dv = v - mean;
    red[t] = dv * dv; __syncthreads();
    for (int o = 128; o > 0; o >>= 1) { if (t < o) red[t] += red[t + o]; __syncthreads(); }
    float var = red[0] / D_;
    y[(long)row * D_ + t] = __float2bfloat16(dv * rsqrtf(var + 1e-5f) * g[t] + b[t]);
}

// ---------------- weight transpose+convert: W[K][N] fp32 -> WT[N][K] bf16 (+bqkv concat) ----------------
__global__ __launch_bounds__(256) void conv_w(const float* w0, const float* w1, const float* w2,
                                              const float* w3, const float* w4, const float* w5,
                                              const float* w6,
                                              const float* bq, const float* bk, const float* bv,
                                              bf16_t* wt, float* bqkv) {
    __shared__ float tile[32][33];
    int tb = blockIdx.x;
    if (tb >= 896) {     // bias concat blocks
        int t = (tb - 896) * 256 + threadIdx.x;   // 0..767
        if (t < 768) bqkv[t] = t < 256 ? bq[t] : (t < 512 ? bk[t - 256] : bv[t - 512]);
        return;
    }
    const float* W; long dstoff; int K, N, local;
    if (tb < 64)       { W = w0; dstoff = 0;       K = 256;  N = 256;  local = tb; }
    else if (tb < 128) { W = w1; dstoff = 65536;   K = 256;  N = 256;  local = tb - 64; }
    else if (tb < 192) { W = w2; dstoff = 131072;  K = 256;  N = 256;  local = tb - 128; }
    else if (tb < 256) { W = w3; dstoff = 196608;  K = 256;  N = 256;  local = tb - 192; }
    else if (tb < 384) { W = w4; dstoff = 262144;  K = 512;  N = 256;  local = tb - 256; }
    else if (tb < 640) { W = w5; dstoff = 393216;  K = 256;  N = 1024; local = tb - 384; }
    else               { W = w6; dstoff = 655360;  K = 1024; N = 256;  local = tb - 640; }
    int ntn = N >> 5;
    int tk = local / ntn, tn = local - tk * ntn;
    int k0 = tk * 32, n0 = tn * 32;
    int r = threadIdx.x >> 5, c = threadIdx.x & 31;
#pragma unroll
    for (int rr = 0; rr < 4; rr++)
        tile[r + rr * 8][c] = W[(long)(k0 + r + rr * 8) * N + n0 + c];
    __syncthreads();
    bf16_t* dst = wt + dstoff;
#pragma unroll
    for (int rr = 0; rr < 4; rr++)
        dst[(long)(n0 + r + rr * 8) * K + k0 + c] = __float2bfloat16(tile[c][r + rr * 8]);
}

// ---------------- MFMA bf16 GEMM, 64x64 tile, BK=64: C = A[M,K] @ WT[N,K]^T ----------------
#define LDT64 72

template<int GELU>
__global__ __launch_bounds__(256) void mgemm64(const bf16_t* __restrict__ A,
                                               const bf16_t* __restrict__ Wt,
                                               const float* __restrict__ bias,
                                               const float* __restrict__ resid,
                                               float* __restrict__ Cf,
                                               bf16_t* __restrict__ Cb,
                                               int M, int N, int K, int ldcb) {
    __shared__ short As[64 * LDT64];
    __shared__ short Bs[64 * LDT64];
    int tid = threadIdx.x;
    int m0 = blockIdx.y * 64, n0 = blockIdx.x * 64;
    int w = tid >> 6, ln = tid & 63;
    int wr = w >> 1, wc = w & 1;
    int srow = tid >> 2, skb = (tid & 3) * 8;
    f32x4 zero4 = {0.f, 0.f, 0.f, 0.f};
    f32x4 acc[2][2];
#pragma unroll
    for (int i = 0; i < 2; i++)
#pragma unroll
        for (int j = 0; j < 2; j++) acc[i][j] = zero4;

    const bf16_t* Ab = A + (long)m0 * K + skb;
    const bf16_t* Bb = Wt + (long)n0 * K + skb;

    for (int k0 = 0; k0 < K; k0 += 64) {
        uint4 a0 = *(const uint4*)(Ab + (long)srow * K + k0);
        uint4 a1 = *(const uint4*)(Ab + (long)srow * K + k0 + 32);
        uint4 b0 = *(const uint4*)(Bb + (long)srow * K + k0);
        uint4 b1 = *(const uint4*)(Bb + (long)srow * K + k0 + 32);
        *(uint4*)(&As[srow * LDT64 + skb]) = a0;
        *(uint4*)(&As[srow * LDT64 + skb + 32]) = a1;
        *(uint4*)(&Bs[srow * LDT64 + skb]) = b0;
        *(uint4*)(&Bs[srow * LDT64 + skb + 32]) = b1;
        __syncthreads();
        int kr = (ln >> 4) * 8;
        int arow = wr * 32 + (ln & 15);
        int brow = wc * 32 + (ln & 15);
        bf16x8 af[2][2], bfr[2][2];
#pragma unroll
        for (int mi = 0; mi < 2; mi++)
#pragma unroll
            for (int ks = 0; ks < 2; ks++)
                af[mi][ks] = *(const bf16x8*)(&As[(arow + mi * 16) * LDT64 + ks * 32 + kr]);
#pragma unroll
        for (int ni = 0; ni < 2; ni++)
#pragma unroll
            for (int ks = 0; ks < 2; ks++)
                bfr[ni][ks] = *(const bf16x8*)(&Bs[(brow + ni * 16) * LDT64 + ks * 32 + kr]);
#pragma unroll
        for (int mi = 0; mi < 2; mi++)
#pragma unroll
            for (int ni = 0; ni < 2; ni++) {
                acc[mi][ni] = __builtin_amdgcn_mfma_f32_16x16x32_bf16(af[mi][0], bfr[ni][0], acc[mi][ni], 0, 0, 0);
                acc[mi][ni] = __builtin_amdgcn_mfma_f32_16x16x32_bf16(af[mi][1], bfr[ni][1], acc[mi][ni], 0, 0, 0);
            }
        __syncthreads();
    }
    // epilogue: D[row=(l>>4)*4+r][col=l&15] per 16x16 frag (m89-verified layout)
    int colb = n0 + wc * 32 + (ln & 15);
    int rowb = m0 + wr * 32 + (ln >> 4) * 4;
#pragma unroll
    for (int ni = 0; ni < 2; ni++) {
        int col = colb + ni * 16;
        float bv = bias ? bias[col] : 0.f;
#pragma unroll
        for (int mi = 0; mi < 2; mi++) {
#pragma unroll
            for (int r = 0; r < 4; r++) {
                int row = rowb + mi * 16 + r;
                float v = acc[mi][ni][r] + bv;
                if (GELU) v = 0.5f * v * (1.0f + erff(v * 0.70710678118654752f));
                if (resid) v += resid[(long)row * N + col];
                if (Cf) Cf[(long)row * N + col] = v;
                if (Cb) Cb[(long)row * ldcb + col] = __float2bfloat16(v);
            }
        }
    }
}

// ---------------- v column sums (v = qkv_bf[:, 512:768]), two-stage ----------------
__global__ void vsum1(const bf16_t* __restrict__ qkv, float* __restrict__ part) {
    int b = blockIdx.x >> 6, ch = blockIdx.x & 63;
    int c = threadIdx.x;
    float s = 0.f;
    int j0 = ch * 32;
    for (int j = j0; j < j0 + 32; j++)
        s += __bfloat162float(qkv[((long)b * S_ + j) * 768 + 512 + c]);
    part[(long)blockIdx.x * QK_ + c] = s;
}

__global__ void vsum2(const float* __restrict__ part, float* __restrict__ vs) {
    int g = blockIdx.x * 256 + threadIdx.x;   // 0..511
    int b = g >> 8, c = g & 255;
    float s = 0.f;
    for (int ch = 0; ch < 64; ch++) s += part[(long)(b * 64 + ch) * QK_ + c];
    vs[g] = s;
}

// ---------------- sparse attention: quad-coop coalesced K loads, wave-parallel softmax ----------------
__global__ __launch_bounds__(256) void attn_kernel(const bf16_t* __restrict__ qkv,
                                                   const float* __restrict__ vs,
                                                   const int* __restrict__ ridx,
                                                   const int* __restrict__ nbr_idx,
                                                   const int* __restrict__ nbr_cnt,
                                                   bf16_t* __restrict__ out) {
    __shared__ float qs[QK_];
    __shared__ float ej[H_][MAXN_];
    __shared__ int   nb[MAXN_];
    int bi = blockIdx.x;              // b*S + i
    int b = bi >> 11, i = bi & (S_ - 1);
    int t = threadIdx.x;
    int h = t >> 5, ln = t & 31;
    int r = ridx[i];
    int cnt = nbr_cnt[r];
    qs[t] = __bfloat162float(qkv[(long)bi * 768 + t]);
    for (int p = t; p < cnt; p += 256) nb[p] = nbr_idx[r * MAXN_ + p];
    __syncthreads();
    const bf16_t* kvb = qkv + (long)b * S_ * 768;
    int quad = ln & 3, pslot = ln >> 2;
    const float* qh = qs + h * HD_;
    float qreg[8];
#pragma unroll
    for (int e = 0; e < 8; e++) qreg[e] = qh[quad * 8 + e];
    float lmax = 0.0f;                // masked zeros always present (cnt << S)
#pragma unroll 2
    for (int s = 0; s * 8 < cnt; s++) {
        int p = s * 8 + pslot;
        float sc = 0.f;
        if (p < cnt) {
            int j = nb[p];
            bf16x8 kk = *(const bf16x8*)(kvb + (long)j * 768 + 256 + h * HD_ + quad * 8);
#pragma unroll
            for (int e = 0; e < 8; e++) sc = fmaf(qreg[e], bf2f(kk[e]), sc);
        }
        sc += __shfl_xor(sc, 1, 32);
        sc += __shfl_xor(sc, 2, 32);
        sc *= SCALE_;
        if (p < cnt) {
            if (quad == 0) ej[h][p] = sc;   // raw score; same-wave LDS ordering
            lmax = fmaxf(lmax, sc);
        }
    }
#pragma unroll
    for (int o = 16; o > 0; o >>= 1) lmax = fmaxf(lmax, __shfl_xor(lmax, o, 32));
    float lz = 0.f;
#pragma unroll
    for (int u = 0; u < 6; u++) {
        int p = ln + 32 * u;
        if (p < cnt) {
            float e = expf(ej[h][p] - lmax);
            ej[h][p] = e;
            lz += e;
        }
    }
#pragma unroll
    for (int o = 16; o > 0; o >>= 1) lz += __shfl_xor(lz, o, 32);
    float em = expf(-lmax);
    float Z = lz + (float)(S_ - cnt) * em;
    float accv = 0.f, vn = 0.f;
    const bf16_t* vbase = kvb + 512 + h * HD_ + ln;
#pragma unroll 8
    for (int p = 0; p < cnt; p++) {
        int j = nb[p];
        float vv = __bfloat162float(vbase[(long)j * 768]);
        float e = ej[h][p];
        accv = fmaf(e, vv, accv);
        vn += vv;
    }
    float o = (em * (vs[b * QK_ + h * HD_ + ln] - vn) + accv) / Z;
    out[(long)bi * QK_ + h * HD_ + ln] = __float2bfloat16(o);
}

// ---------------- gate + fuse + LN2 (writes fused fp32, h bf16) ----------------
__global__ __launch_bounds__(256) void fuse_ln2_kernel(const float* __restrict__ x,
                                                       const float* __restrict__ ao,
                                                       const float* __restrict__ gp,
                                                       const float* __restrict__ g2,
                                                       const float* __restrict__ b2,
                                                       float* __restrict__ fused,
                                                       bf16_t* __restrict__ h) {
    __shared__ float red[256];
    int row = blockIdx.x, t = threadIdx.x;
    long idx = (long)row * D_ + t;
    float gate = 1.f / (1.f + expf(-gp[idx]));
    float f = gate * x[idx] + (1.f - gate) * ao[idx];
    fused[idx] = f;
    red[t] = f; __syncthreads();
    for (int o = 128; o > 0; o >>= 1) { if (t < o) red[t] += red[t + o]; __syncthreads(); }
    float mean = red[0] / D_;
    __syncthreads();
    float dv = f - mean;
    red[t] = dv * dv; __syncthreads();
    for (int o = 128; o > 0; o >>= 1) { if (t < o) red[t] += red[t + o]; __syncthreads(); }
    float var = red[0] / D_;
    h[idx] = __float2bfloat16(dv * rsqrtf(var + 1e-5f) * g2[t] + b2[t]);
}

extern "C" void kernel_launch(void* const* d_in, const int* in_sizes, int n_in,
                              void* d_out, int out_size, void* d_ws, size_t ws_size,
                              hipStream_t stream) {
    const float* x    = (const float*)d_in[0];
    const int*   ridx = (const int*)d_in[1];
    const void*  adj  = d_in[2];
    const float* rm   = (const float*)d_in[3];
    const float* wq = (const float*)d_in[4],  *bq = (const float*)d_in[5];
    const float* wk = (const float*)d_in[6],  *bk = (const float*)d_in[7];
    const float* wv = (const float*)d_in[8],  *bv = (const float*)d_in[9];
    const float* wo = (const float*)d_in[10], *bo = (const float*)d_in[11];
    const float* ln1g = (const float*)d_in[12], *ln1b = (const float*)d_in[13];
    const float* ln2g = (const float*)d_in[14], *ln2b = (const float*)d_in[15];
    const float* gw  = (const float*)d_in[16], *gb  = (const float*)d_in[17];
    const float* fw1 = (const float*)d_in[18], *fb1 = (const float*)d_in[19];
    const float* fw2 = (const float*)d_in[20], *fb2 = (const float*)d_in[21];
    float* out = (float*)d_out;

    // workspace layout (float units; all offsets 16B-aligned)
    float* wsf      = (float*)d_ws;
    int*   flag     = (int*)d_ws;                  // @0 (64)
    bf16_t* nm_bf   = (bf16_t*)(wsf + 64);         // 2048*64 bf16 in 131072-fl slot
    int*   tk       = (int*)(wsf + 64 + 131072);   // 16384
    int*   nbr_idx  = tk + 16384;                  // 393216
    int*   nbr_cnt  = nbr_idx + R_ * MAXN_;        // 2048
    bf16_t* qkv_bf  = (bf16_t*)(nbr_cnt + 2048);   // 4096*768 bf16 (in 3145728-fl slot)
    float* vs       = (float*)(nbr_cnt + 2048) + 3145728;  // 512
    float* gatep    = vs + 512;                    // 1048576
    float* attn_out = gatep + 1048576;             // 1048576
    float* fusedb   = attn_out + 1048576;          // 1048576
    float* part     = fusedb + 1048576;            // 32768
    bf16_t* xn_bf   = (bf16_t*)(part + 32768);     // 1048576 bf16 (524288 fl)
    bf16_t* attnO_bf= (bf16_t*)((float*)xn_bf + 524288);    // 1048576 bf16
    bf16_t* xcat_bf = (bf16_t*)((float*)attnO_bf + 524288); // 4096*512 bf16 (1048576 fl)
    bf16_t* hb_bf   = (bf16_t*)((float*)xcat_bf + 1048576); // 1048576 bf16
    bf16_t* f1_bf   = (bf16_t*)((float*)hb_bf + 524288);    // 4096*1024 bf16 (2097152 fl)
    bf16_t* WT      = (bf16_t*)((float*)f1_bf + 2097152);   // 917504 bf16 (458752 fl)
    float* bqkv     = (float*)WT + 458752;         // 768
    float* sim      = bqkv + 768;                  // R*R = 4194304 (16 MB)

    const int MROWS = B_ * S_;                     // 4096

    norm_rm<<<R_, 64, 0, stream>>>(rm, nm_bf, flag);        // also inits flag=0
    detect_adj<<<256, 256, 0, stream>>>((const unsigned int*)adj, flag);

    // sim = nm @ nm^T via MFMA (M=N=2048, K=64), then 0-barrier top-8 selection
    mgemm64<0><<<dim3(R_ / 64, R_ / 64), 256, 0, stream>>>(
        nm_bf, nm_bf, nullptr, nullptr, sim, nullptr, R_, R_, MD_, 0);
    topk_sel<<<R_ / 4, 256, 0, stream>>>(sim, tk);

    build_nbr<<<R_, 256, 0, stream>>>(adj, tk, flag, nbr_idx, nbr_cnt);

    conv_w<<<899, 256, 0, stream>>>(wq, wk, wv, wo, gw, fw1, fw2, bq, bk, bv, WT, bqkv);

    ln_kernel<<<MROWS, 256, 0, stream>>>(x, ln1g, ln1b, xn_bf, xcat_bf);

    // QKV fused: [4096,256] @ [256,768] -> qkv bf16 [4096][768]
    mgemm64<0><<<dim3(768 / 64, MROWS / 64), 256, 0, stream>>>(
        xn_bf, WT + 0, bqkv, nullptr, nullptr, qkv_bf, MROWS, 768, 256, 768);

    vsum1<<<B_ * 64, 256, 0, stream>>>(qkv_bf, part);
    vsum2<<<2, 256, 0, stream>>>(part, vs);
    attn_kernel<<<MROWS, 256, 0, stream>>>(qkv_bf, vs, ridx, nbr_idx, nbr_cnt, attnO_bf);

    // wo: attnO @ wo + bo -> attn_out fp32; bf16 copy into xcat cols 256..511
    mgemm64<0><<<dim3(256 / 64, MROWS / 64), 256, 0, stream>>>(
        attnO_bf, WT + 196608, bo, nullptr, attn_out, xcat_bf + 256, MROWS, 256, 256, 512);

    // gate: [x | attn_out] @ gw + gb -> gatep fp32   (K=512)
    mgemm64<0><<<dim3(256 / 64, MROWS / 64), 256, 0, stream>>>(
        xcat_bf, WT + 262144, gb, nullptr, gatep, nullptr, MROWS, 256, 512, 0);

    fuse_ln2_kernel<<<MROWS, 256, 0, stream>>>(x, attn_out, gatep, ln2g, ln2b, fusedb, hb_bf);

    // FFN1: h @ w1 + b1, gelu -> f1 bf16
    mgemm64<1><<<dim3(1024 / 64, MROWS / 64), 256, 0, stream>>>(
        hb_bf, WT + 393216, fb1, nullptr, nullptr, f1_bf, MROWS, 1024, 256, 1024);

    // FFN2: f1 @ w2 + b2 + fused -> out fp32
    mgemm64<0><<<dim3(256 / 64, MROWS / 64), 256, 0, stream>>>(
        f1_bf, WT + 655360, fb2, fusedb, out, nullptr, MROWS, 256, 1024, 0);
}